// Round 6
// baseline (228579.663 us; speedup 1.0000x reference)
//
#include <hip/hip_runtime.h>
#include <hip/hip_bf16.h>
#include <hip/hip_fp16.h>

// LSTM T=8192, IN=MEM=2048.
// Phase 1: x_proj[t][g] = inputs[t]·Wx[g] + bx[g] + bh[g], stored fp16 in ws (128 MB).
// Phase 2: spin-flag recurrence, 256 blocks x 256 thr, launch_bounds(256,1) ->
//          1 block/CU resident under ANY reg allocation (deadlock-immune by
//          construction) + bounded spin (never hangs the container).
//          Wh stationary in regs as packed fp16 (128 VGPR), MAC via v_dot2_f32_f16.

#define T_STEPS 8192
#define IN_D    2048
#define MEM_D   2048
#define G4      8192      // 4*MEM_D
#define NBLK    256       // recurrence blocks (1 per CU, guaranteed resident)
#define HPB     8         // h elements per block
#define RPB     32        // Wh rows per block (4 gates x HPB)
#define SPIN_MAX 2000000  // bounded spin: ~0.1s worst case, then proceed (no hang)

typedef unsigned long long ull;
typedef _Float16 h2 __attribute__((ext_vector_type(2)));

#if __has_builtin(__builtin_amdgcn_fdot2)
__device__ __forceinline__ float fdot2(h2 a, h2 b, float c) {
  return __builtin_amdgcn_fdot2(a, b, c, false);
}
#else
__device__ __forceinline__ float fdot2(h2 a, h2 b, float c) {
  return fmaf((float)a.x, (float)b.x, fmaf((float)a.y, (float)b.y, c));
}
#endif

// ---------------- Phase 1: x_proj GEMM (fp32 in, fp16 out) ----------------
// 128(t) x 64(g) tile, 256 threads, per-thread 8x4 acc, K-step 32, b128 LDS reads.
__global__ __launch_bounds__(256) void xproj_gemm(
    const float* __restrict__ A,      // inputs (8192, 2048), K-contig
    const float* __restrict__ Bw,     // Wx     (8192, 2048), K-contig
    const float* __restrict__ bx,
    const float* __restrict__ bh,
    __half* __restrict__ xp)          // (8192, 8192)
{
  __shared__ float As[128][36];   // pad 36 (mult of 4): 16B-aligned b128 reads
  __shared__ float Bs[64][36];
  const int tid = threadIdx.x;
  const int tx = tid & 15;        // gate sub-index
  const int ty = tid >> 4;        // time sub-index
  const int g0 = blockIdx.x * 64;
  const int t0 = blockIdx.y * 128;
  float acc[8][4] = {};

  for (int k0 = 0; k0 < IN_D; k0 += 32) {
#pragma unroll
    for (int l = 0; l < 4; ++l) {           // As: 128 rows x 32 cols
      int fi = tid + l * 256;
      int row = fi >> 3;
      int c4 = (fi & 7) * 4;
      *(float4*)(&As[row][c4]) = *(const float4*)(&A[(size_t)(t0 + row) * IN_D + k0 + c4]);
    }
#pragma unroll
    for (int l = 0; l < 2; ++l) {           // Bs: 64 rows x 32 cols
      int fi = tid + l * 256;
      int row = fi >> 3;
      int c4 = (fi & 7) * 4;
      *(float4*)(&Bs[row][c4]) = *(const float4*)(&Bw[(size_t)(g0 + row) * IN_D + k0 + c4]);
    }
    __syncthreads();
#pragma unroll
    for (int kk = 0; kk < 32; kk += 4) {
      float4 a[8], b[4];
#pragma unroll
      for (int i = 0; i < 8; ++i) a[i] = *(const float4*)(&As[ty + i*16][kk]);
#pragma unroll
      for (int j = 0; j < 4; ++j) b[j] = *(const float4*)(&Bs[tx + j*16][kk]);
#pragma unroll
      for (int i = 0; i < 8; ++i)
#pragma unroll
        for (int j = 0; j < 4; ++j) {
          acc[i][j] += a[i].x * b[j].x;
          acc[i][j] += a[i].y * b[j].y;
          acc[i][j] += a[i].z * b[j].z;
          acc[i][j] += a[i].w * b[j].w;
        }
    }
    __syncthreads();
  }

  float bias[4];
#pragma unroll
  for (int j = 0; j < 4; ++j) {
    int c = g0 + tx + j*16;
    bias[j] = bx[c] + bh[c];
  }
#pragma unroll
  for (int i = 0; i < 8; ++i) {
    int r = t0 + ty + i*16;
#pragma unroll
    for (int j = 0; j < 4; ++j) {
      int c = g0 + tx + j*16;
      xp[(size_t)r * G4 + c] = __float2half(acc[i][j] + bias[j]);
    }
  }
}

// ---------------- Phase 2: recurrence ----------------
// Block b owns h[b*8 .. b*8+8); local row = gate*8 + e (gate in {i,o,f,u}).
// Thread (row = tid&31, cs = tid>>5): 256-col fp16 weight segment in 128 VGPRs.
// Step: [prefetch xp] -> poll flags[(t-1)&1][tid]==t-1 (bounded; thread tid polls
// the exact producer block of the h-slice it gathers) -> gather h (fp16, 16B/thr)
// -> LDS -> fdot2 MAC -> xor32 + LDS reduce -> gates on 8 lanes ->
// publish h (fp16, 4B-packed atomics) + flag[t&1][b]=t (release).
// Depth-2 safety: publishing h(t) needs all h(t-1) read; every block published t-1
// only after its reads of h(t-2) completed -> no overwrite of a buffer in use.
__global__ __launch_bounds__(256, 1) void lstm_rec(
    const float* __restrict__ Wh,            // (8192, 2048)
    const __half* __restrict__ xp,           // (8192, 8192)
    unsigned int* __restrict__ hbuf,         // 2 phases * 1024 uints (2048 fp16)
    int* __restrict__ flags,                 // 2 * NBLK
    float* __restrict__ out)                 // 2048
{
  __shared__ __align__(16) __half hl[2048];   // h broadcast (4KB)
  __shared__ float pa[4][RPB];                // per-wave partials
  const int tid = threadIdx.x;
  const int b = blockIdx.x;
  const int row = tid & 31;
  const int cs = tid >> 5;            // 8 segments x 256 cols
  const int gate = row >> 3, e = row & 7;
  const int wid = tid >> 6;

  // Publish h(-1)=0 with tag -1 FIRST (unblocks everyone; handles ws poison).
  if (tid < HPB / 2)
    __hip_atomic_store(&hbuf[1024 + b * (HPB/2) + tid], 0u,
                       __ATOMIC_RELAXED, __HIP_MEMORY_SCOPE_AGENT);
  if (tid == 0)
    __hip_atomic_store(&flags[NBLK + b], -1,
                       __ATOMIC_RELEASE, __HIP_MEMORY_SCOPE_AGENT);

  // Stationary weights: 256 fp32 -> 128 packed-fp16 VGPRs.
  h2 wreg[128];
  {
    const float4* wr = (const float4*)(&Wh[(size_t)(gate * MEM_D + b * HPB + e) * MEM_D + cs * 256]);
#pragma unroll
    for (int i = 0; i < 64; ++i) {
      float4 v = wr[i];
      wreg[2*i]   = h2{(_Float16)v.x, (_Float16)v.y};
      wreg[2*i+1] = h2{(_Float16)v.z, (_Float16)v.w};
    }
  }

  float c_state = 0.0f;
  bool dead = false;

  for (int t = 0; t < T_STEPS; ++t) {
    // Prefetch x_proj (independent of h -> hidden under the poll stall).
    float xpv = 0.0f;
    if (tid < RPB)
      xpv = __half2float(xp[(size_t)t * G4 + (tid >> 3) * MEM_D + b * HPB + (tid & 7)]);

    const int want = t - 1;
    const int p = want & 1;
    if (!dead) {
      int spins = 0;
      while (__hip_atomic_load(&flags[p * NBLK + tid], __ATOMIC_ACQUIRE,
                               __HIP_MEMORY_SCOPE_AGENT) != want) {
        __builtin_amdgcn_s_sleep(1);
        if (++spins > SPIN_MAX) { dead = true; break; }   // never hang the container
      }
    }

    // Gather 16B of h (8 fp16) per thread, coherent 8B loads -> LDS.
    {
      const ull* hp = (const ull*)(&hbuf[p * 1024]);
      ull lo = __hip_atomic_load(&hp[tid*2+0], __ATOMIC_RELAXED, __HIP_MEMORY_SCOPE_AGENT);
      ull hi = __hip_atomic_load(&hp[tid*2+1], __ATOMIC_RELAXED, __HIP_MEMORY_SCOPE_AGENT);
      ull* dst = (ull*)(&hl[tid * 8]);    // 16B-aligned (tid*8 halves)
      dst[0] = lo; dst[1] = hi;
    }
    __syncthreads();

    // MAC: 256 fp16 cols via 32 ds_read_b128 (2-addr broadcast) + 128 fdot2.
    const uint4* hseg = ((const uint4*)hl) + cs * 32;
    float a0 = 0.0f, a1 = 0.0f;
#pragma unroll
    for (int q = 0; q < 32; q += 2) {
      uint4 x0 = hseg[q];
      uint4 x1 = hseg[q + 1];
      a0 = fdot2(wreg[q*4+0], __builtin_bit_cast(h2, x0.x), a0);
      a0 = fdot2(wreg[q*4+1], __builtin_bit_cast(h2, x0.y), a0);
      a0 = fdot2(wreg[q*4+2], __builtin_bit_cast(h2, x0.z), a0);
      a0 = fdot2(wreg[q*4+3], __builtin_bit_cast(h2, x0.w), a0);
      a1 = fdot2(wreg[q*4+4], __builtin_bit_cast(h2, x1.x), a1);
      a1 = fdot2(wreg[q*4+5], __builtin_bit_cast(h2, x1.y), a1);
      a1 = fdot2(wreg[q*4+6], __builtin_bit_cast(h2, x1.z), a1);
      a1 = fdot2(wreg[q*4+7], __builtin_bit_cast(h2, x1.w), a1);
    }
    float acc = a0 + a1;
    acc += __shfl_xor(acc, 32);          // combine the wave's 2 cs-groups
    if ((tid & 63) < 32) pa[wid][row] = acc;
    __syncthreads();                      // also fences hl reads before next overwrite

    if (tid < 64) {   // wave 0 finishes: reduce, gates, publish
      float dot = pa[0][row] + pa[1][row] + pa[2][row] + pa[3][row];
      float pre = dot + xpv;              // valid in lanes 0..31
      float pi = __shfl(pre,      e);
      float po = __shfl(pre,  8 + e);
      float pf = __shfl(pre, 16 + e);
      float pu = __shfl(pre, 24 + e);
      if (tid < HPB) {
        float si = 1.0f / (1.0f + __expf(-pi));
        float so = 1.0f / (1.0f + __expf(-po));
        float sf = 1.0f / (1.0f + __expf(-pf));
        float tu = 1.0f - 2.0f / (__expf(2.0f * pu) + 1.0f);
        c_state = si * tu + sf * c_state;
        float th = 1.0f - 2.0f / (__expf(2.0f * c_state) + 1.0f);
        float h = so * th;
        if (t == T_STEPS - 1) out[b * HPB + tid] = h;
        // Pack pairs -> 4B atomic stores by even lanes.
        unsigned int hu = (unsigned int)__half_as_ushort(__float2half(h));
        unsigned int partner = (unsigned int)__shfl((int)hu, tid + 1);
        if ((tid & 1) == 0)
          __hip_atomic_store(&hbuf[(t & 1) * 1024 + b * (HPB/2) + (tid >> 1)],
                             hu | (partner << 16),
                             __ATOMIC_RELAXED, __HIP_MEMORY_SCOPE_AGENT);
      }
    }
    // Release: wave-level vmcnt(0) drains lanes 0..7's h stores before the flag
    // (same wave as tid==0 -> its waitcnt covers their vmem ops).
    if (tid == 0)
      __hip_atomic_store(&flags[(t & 1) * NBLK + b], t,
                         __ATOMIC_RELEASE, __HIP_MEMORY_SCOPE_AGENT);
  }
}

extern "C" void kernel_launch(void* const* d_in, const int* in_sizes, int n_in,
                              void* d_out, int out_size, void* d_ws, size_t ws_size,
                              hipStream_t stream) {
  const float* inputs = (const float*)d_in[0];
  const float* Wx     = (const float*)d_in[1];
  const float* bx     = (const float*)d_in[2];
  const float* Wh     = (const float*)d_in[3];
  const float* bh     = (const float*)d_in[4];
  float* out = (float*)d_out;

  char* ws = (char*)d_ws;
  __half* xp = (__half*)ws;
  const size_t xp_bytes = (size_t)T_STEPS * G4 * sizeof(__half);  // 128 MB
  unsigned int* hbuf = (unsigned int*)(ws + xp_bytes);            // 8 KB
  int* flags = (int*)(ws + xp_bytes + 8192);                      // 2 KB

  dim3 gg(G4 / 64, T_STEPS / 128);
  xproj_gemm<<<gg, dim3(256), 0, stream>>>(inputs, Wx, bx, bh, xp);
  lstm_rec<<<dim3(NBLK), dim3(256), 0, stream>>>(Wh, xp, hbuf, flags, out);
}